// Round 4
// baseline (435.809 us; speedup 1.0000x reference)
//
#include <hip/hip_runtime.h>
#include <hip/hip_bf16.h>

#define S_LEN 2048
#define DMODEL 4096
#define NH 32
#define NKV 8
#define HD 128
#define NQKV 6144
#define ATT_SCALE 0.08838834764831845f  // 1/sqrt(128)

typedef __bf16 bf16x8 __attribute__((ext_vector_type(8)));
typedef float f32x4 __attribute__((ext_vector_type(4)));

// float -> bf16 bits, round-to-nearest-even
__device__ __forceinline__ unsigned short f2b(float f) {
  union { float f; unsigned u; } a; a.f = f;
  unsigned u = a.u;
  return (unsigned short)((u + 0x7FFFu + ((u >> 16) & 1u)) >> 16);
}

__device__ __forceinline__ void gl16(const unsigned short* g, unsigned short* l) {
  __builtin_amdgcn_global_load_lds(
      (const __attribute__((address_space(1))) unsigned int*)g,
      (__attribute__((address_space(3))) unsigned int*)l, 16, 0, 0);
}

// ---------------- x fp32 -> bf16 ----------------
__global__ __launch_bounds__(256) void k_cvt_x(const float* __restrict__ x,
                                               unsigned short* __restrict__ xb) {
  int i = blockIdx.x * 256 + threadIdx.x;
  float4 v = ((const float4*)x)[i];
  ushort4 o;
  o.x = f2b(v.x); o.y = f2b(v.y); o.z = f2b(v.z); o.w = f2b(v.w);
  ((ushort4*)xb)[i] = o;
}

// ------------- W (K,N) fp32 -> Wt (N,K) bf16 -------------
__global__ __launch_bounds__(256) void k_transpose(const float* __restrict__ W,
                                                   unsigned short* __restrict__ Wt,
                                                   int K, int N) {
  __shared__ float tile[64][65];
  int k0 = blockIdx.x * 64, n0 = blockIdx.y * 64;
  int tx = threadIdx.x & 31, ty = threadIdx.x >> 5;
#pragma unroll
  for (int i = 0; i < 8; ++i) {
    int k = ty + i * 8;
    const float* src = W + (size_t)(k0 + k) * N + n0;
    tile[k][tx] = src[tx];
    tile[k][tx + 32] = src[tx + 32];
  }
  __syncthreads();
#pragma unroll
  for (int i = 0; i < 8; ++i) {
    int n = ty + i * 8;
    unsigned short* dst = Wt + (size_t)(n0 + n) * K + k0;
    dst[tx] = f2b(tile[tx][n]);
    dst[tx + 32] = f2b(tile[tx + 32][n]);
  }
}

// ------------- V [S][NKV][HD] bf16 -> V^T [NKV][HD][S] bf16 -------------
__global__ __launch_bounds__(256) void k_vt(const unsigned short* __restrict__ v_bf,
                                            unsigned short* __restrict__ v_t) {
  __shared__ unsigned short tile[64][65];
  int s0 = blockIdx.x * 64, d0 = blockIdx.y * 64, kvh = blockIdx.z;
  int tx = threadIdx.x & 63, ty = threadIdx.x >> 6;
#pragma unroll
  for (int i = 0; i < 16; ++i) {
    int s = ty + i * 4;
    tile[s][tx] = v_bf[((size_t)(s0 + s) * NKV + kvh) * HD + d0 + tx];
  }
  __syncthreads();
#pragma unroll
  for (int i = 0; i < 16; ++i) {
    int d = ty + i * 4;
    v_t[((size_t)kvh * HD + d0 + d) * S_LEN + s0 + tx] = tile[tx][d];
  }
}

// ============ 256x256 8-phase GEMM: C(MxN) fp32 = A(MxK) bf16 * Bt(NxK) bf16 ============
// BM=BN=256, BK=64, 512 threads = 8 waves (2Mx4N); per-wave output = two 64-row stripes
// x two 32-col stripes. LDS 128 KB dynamic: A/B x 2 dbuf x 2 halves(16KB). st_16x32 swizzle
// (byte ^= ((byte>>9)&1)<<5) applied via pre-swizzled gl16 source + swizzled ds_read addr.
// Counted vmcnt(6) once per K-tile (T4); raw s_barrier only; setprio around MFMA (T5).
__global__ __launch_bounds__(512, 2) void k_gemm256(const unsigned short* __restrict__ A,
                                                    const unsigned short* __restrict__ B,
                                                    float* __restrict__ C,
                                                    int M, int N, int K) {
  extern __shared__ __align__(16) unsigned short smem[];
  char* Sc = (char*)smem;
  // bytes: A buf b: [b*32768, +32K) half h at +h*16384 ; B buf b: [65536 + b*32768, ...)
  const int tid = threadIdx.x;
  const int wvid = tid >> 6, l = tid & 63;
  const int wm = wvid >> 2, wn = wvid & 3;
  const int l15 = l & 15, l4 = l >> 4;

  // XCD-bijective swizzle (grid % 8 == 0 for both call sites)
  const int nwg = gridDim.x;
  const int cpx = nwg >> 3;
  const int bid = blockIdx.x;
  const int swz = (bid & 7) * cpx + (bid >> 3);
  const int mtiles = M >> 8;
  const int m0 = (swz % mtiles) * 256;
  const int n0 = (swz / mtiles) * 256;

  const int NT = K >> 6;

  // read-side swizzled column offset (bytes): l4*16 with bit5 ^= row-bit2 (= l15 bit2)
  const int col_off = (l4 * 16) ^ (((l15 >> 2) & 1) << 5);
  const int a_base = (wm * 64 + l15) * 128 + col_off;   // within a 16 KB half
  const int b_base = (wn * 32 + l15) * 128 + col_off;

  // stage-side: linear dest slot -> pre-swizzled global (row, k8)
  const int lane_off = (l * 16) ^ (((l >> 5) & 1) << 5);
  const int st_row = lane_off >> 7;          // 0..7
  const int st_k8 = (lane_off >> 4) & 7;     // k-slot (8 elems)

  auto stA = [&](int tt, int h) {
    if (tt >= NT) return;
    const unsigned short* g = A + (size_t)(m0 + h * 128) * K + tt * 64 + st_k8 * 8;
    unsigned short* lb = (unsigned short*)(Sc + (tt & 1) * 32768 + h * 16384);
#pragma unroll
    for (int j = 0; j < 2; ++j) {
      int blk = j * 8 + wvid;
      gl16(g + (size_t)(blk * 8 + st_row) * K, lb + blk * 512);
    }
  };
  auto stB = [&](int tt, int c) {
    if (tt >= NT) return;
    const unsigned short* g = B + (size_t)(n0 + c * 128) * K + tt * 64 + st_k8 * 8;
    unsigned short* lb = (unsigned short*)(Sc + 65536 + (tt & 1) * 32768 + c * 16384);
#pragma unroll
    for (int j = 0; j < 2; ++j) {
      int blk = j * 8 + wvid;
      gl16(g + (size_t)(blk * 8 + st_row) * K, lb + blk * 512);
    }
  };

  f32x4 acc[2][4][2][2] = {};

  // ---- prologue: steady-state issue order A0,B1,A1,B0(t) ----
  stA(0, 0); stB(0, 1); stA(0, 1); stB(0, 0);
  stA(1, 0); stB(1, 1); stA(1, 1);
  if (NT > 1) asm volatile("s_waitcnt vmcnt(6)" ::: "memory");
  else        asm volatile("s_waitcnt vmcnt(0)" ::: "memory");
  __builtin_amdgcn_s_barrier();

  for (int t = 0; t < NT; ++t) {
    const int b = t & 1;
    const char* Ab = Sc + b * 32768;
    const char* Bb = Sc + 65536 + b * 32768;
    bf16x8 a[4][2], bb[2][2];

    // ===== phase 1: (h0,c0) — read A-h0(8) + B-h0(4); stage B0(t+1) =====
#pragma unroll
    for (int fm = 0; fm < 4; ++fm)
#pragma unroll
      for (int ks = 0; ks < 2; ++ks)
        a[fm][ks] = *(const bf16x8*)(Ab + a_base + fm * 2048 + ks * 64);
#pragma unroll
    for (int fn = 0; fn < 2; ++fn)
#pragma unroll
      for (int ks = 0; ks < 2; ++ks)
        bb[fn][ks] = *(const bf16x8*)(Bb + b_base + fn * 2048 + ks * 64);
    stB(t + 1, 0);
    __builtin_amdgcn_s_barrier();
    __builtin_amdgcn_s_setprio(1);
#pragma unroll
    for (int fm = 0; fm < 4; ++fm)
#pragma unroll
      for (int fn = 0; fn < 2; ++fn)
#pragma unroll
        for (int ks = 0; ks < 2; ++ks)
          acc[0][fm][0][fn] = __builtin_amdgcn_mfma_f32_16x16x32_bf16(a[fm][ks], bb[fn][ks], acc[0][fm][0][fn], 0, 0, 0);
    __builtin_amdgcn_s_setprio(0);
    __builtin_amdgcn_s_barrier();

    // ===== phase 2: (h0,c1) — read B-h1(4); stage A0(t+2) =====
#pragma unroll
    for (int fn = 0; fn < 2; ++fn)
#pragma unroll
      for (int ks = 0; ks < 2; ++ks)
        bb[fn][ks] = *(const bf16x8*)(Bb + 16384 + b_base + fn * 2048 + ks * 64);
    stA(t + 2, 0);
    __builtin_amdgcn_s_barrier();
    __builtin_amdgcn_s_setprio(1);
#pragma unroll
    for (int fm = 0; fm < 4; ++fm)
#pragma unroll
      for (int fn = 0; fn < 2; ++fn)
#pragma unroll
        for (int ks = 0; ks < 2; ++ks)
          acc[0][fm][1][fn] = __builtin_amdgcn_mfma_f32_16x16x32_bf16(a[fm][ks], bb[fn][ks], acc[0][fm][1][fn], 0, 0, 0);
    __builtin_amdgcn_s_setprio(0);
    __builtin_amdgcn_s_barrier();

    // ===== phase 3: (h1,c1) — read A-h1(8); stage B1(t+2); B-h1 held in regs =====
#pragma unroll
    for (int fm = 0; fm < 4; ++fm)
#pragma unroll
      for (int ks = 0; ks < 2; ++ks)
        a[fm][ks] = *(const bf16x8*)(Ab + 16384 + a_base + fm * 2048 + ks * 64);
    stB(t + 2, 1);
    __builtin_amdgcn_s_barrier();
    __builtin_amdgcn_s_setprio(1);
#pragma unroll
    for (int fm = 0; fm < 4; ++fm)
#pragma unroll
      for (int fn = 0; fn < 2; ++fn)
#pragma unroll
        for (int ks = 0; ks < 2; ++ks)
          acc[1][fm][1][fn] = __builtin_amdgcn_mfma_f32_16x16x32_bf16(a[fm][ks], bb[fn][ks], acc[1][fm][1][fn], 0, 0, 0);
    __builtin_amdgcn_s_setprio(0);
    __builtin_amdgcn_s_barrier();

    // ===== phase 4: (h1,c0) — read B-h0(4); stage A1(t+2); boundary vmcnt =====
#pragma unroll
    for (int fn = 0; fn < 2; ++fn)
#pragma unroll
      for (int ks = 0; ks < 2; ++ks)
        bb[fn][ks] = *(const bf16x8*)(Bb + b_base + fn * 2048 + ks * 64);
    stA(t + 2, 1);
    __builtin_amdgcn_s_barrier();
    __builtin_amdgcn_s_setprio(1);
#pragma unroll
    for (int fm = 0; fm < 4; ++fm)
#pragma unroll
      for (int fn = 0; fn < 2; ++fn)
#pragma unroll
        for (int ks = 0; ks < 2; ++ks)
          acc[1][fm][0][fn] = __builtin_amdgcn_mfma_f32_16x16x32_bf16(a[fm][ks], bb[fn][ks], acc[1][fm][0][fn], 0, 0, 0);
    __builtin_amdgcn_s_setprio(0);
    if (t + 1 < NT) {
      if (t + 1 == NT - 1) asm volatile("s_waitcnt vmcnt(0)" ::: "memory");
      else                 asm volatile("s_waitcnt vmcnt(6)" ::: "memory");
    }
    __builtin_amdgcn_s_barrier();
  }

  // ---- epilogue: C write ----
#pragma unroll
  for (int h = 0; h < 2; ++h)
#pragma unroll
    for (int fm = 0; fm < 4; ++fm) {
      int row0 = m0 + h * 128 + wm * 64 + fm * 16 + l4 * 4;
#pragma unroll
      for (int c = 0; c < 2; ++c)
#pragma unroll
        for (int fn = 0; fn < 2; ++fn) {
          int col = n0 + c * 128 + wn * 32 + fn * 16 + l15;
#pragma unroll
          for (int r = 0; r < 4; ++r)
            C[(size_t)(row0 + r) * N + col] = acc[h][fm][c][fn][r];
        }
    }
}

// ------------- RoPE + int8 quantize (stored as bf16 ints) -------------
__global__ __launch_bounds__(256) void k_ropequant(const float* __restrict__ qkv,
                                                   const float* __restrict__ cost,
                                                   const float* __restrict__ sint,
                                                   unsigned short* __restrict__ q_int,
                                                   float* __restrict__ q_ds,
                                                   unsigned short* __restrict__ k_int,
                                                   float* __restrict__ k_ds,
                                                   unsigned short* __restrict__ v_bf) {
  int s = blockIdx.x;
  int wv = threadIdx.x >> 6, l = threadIdx.x & 63;
  int hh = blockIdx.y * 4 + wv;  // 0..47: [0,32) q, [32,40) k, [40,48) v
  const float* row = qkv + (size_t)s * NQKV;
  if (hh < NH + NKV) {
    int off = (hh < NH) ? hh * HD : DMODEL + (hh - NH) * HD;
    float t1 = row[off + l], t2 = row[off + 64 + l];
    float c1 = cost[s * HD + l],      sn1 = sint[s * HD + l];
    float c2 = cost[s * HD + 64 + l], sn2 = sint[s * HD + 64 + l];
    float o1 = t1 * c1 - t2 * sn1;
    float o2 = t2 * c2 + t1 * sn2;
    float amax = fmaxf(fabsf(o1), fabsf(o2));
#pragma unroll
    for (int m = 1; m < 64; m <<= 1) amax = fmaxf(amax, __shfl_xor(amax, m));
    amax = fmaxf(amax, 1e-5f);
    float scale = 127.0f / amax;
    float dscale = amax * (1.0f / 127.0f);
    float v1 = fminf(fmaxf(rintf(o1 * scale), -128.f), 127.f);
    float v2 = fminf(fmaxf(rintf(o2 * scale), -128.f), 127.f);
    if (hh < NH) {
      unsigned short* dst = q_int + ((size_t)s * NH + hh) * HD;
      dst[l] = f2b(v1); dst[l + 64] = f2b(v2);
      if (l == 0) q_ds[(size_t)s * NH + hh] = dscale;
    } else {
      int kh = hh - NH;
      unsigned short* dst = k_int + ((size_t)s * NKV + kh) * HD;
      dst[l] = f2b(v1); dst[l + 64] = f2b(v2);
      if (l == 0) k_ds[(size_t)s * NKV + kh] = dscale;
    }
  } else {
    int vh = hh - (NH + NKV);
    const float* src = row + DMODEL + NKV * HD + vh * HD;
    unsigned short* dst = v_bf + ((size_t)s * NKV + vh) * HD;
    dst[l] = f2b(src[l]);
    dst[l + 64] = f2b(src[l + 64]);
  }
}

// ------------- causal GQA flash attention, paired q-tiles, async dbuf staging -------------
__global__ __launch_bounds__(256) void k_attn(const unsigned short* __restrict__ q_int,
                                              const float* __restrict__ q_ds,
                                              const unsigned short* __restrict__ k_int,
                                              const float* __restrict__ k_ds,
                                              const unsigned short* __restrict__ v_t,
                                              unsigned short* __restrict__ o_bf) {
  __shared__ __align__(16) unsigned short K_lds[2][8192];
  __shared__ __align__(16) unsigned short V_lds[2][8192];
  __shared__ __align__(16) unsigned short P_lds[4][16 * 72];

  const int bid = blockIdx.x;
  const int kvh = bid & 7;
  const int h = kvh * 4 + ((bid >> 3) & 3);
  const int bx = bid >> 5;
  const int tid = threadIdx.x, wv = tid >> 6, l = tid & 63;
  const int l15 = l & 15, l4 = l >> 4;

  auto stage = [&](int b, int kt) {
    const unsigned short* kB = k_int + (size_t)kt * 64 * (NKV * HD) + kvh * HD;
    const unsigned short* vB = v_t + (size_t)kvh * HD * S_LEN + (size_t)kt * 64;
#pragma unroll
    for (int j = 0; j < 4; ++j) {
      int wi = j * 4 + wv;
      int slot = wi * 64 + l;
      int key = slot >> 4;
      int colb = ((slot & 15) * 16) ^ ((key & 7) << 4);
      gl16(kB + key * (NKV * HD) + (colb >> 1), &K_lds[b][wi * 512]);
      int d = slot >> 3;
      int ckb = ((slot & 7) * 16) ^ ((d & 7) << 4);
      gl16(vB + (size_t)d * S_LEN + (ckb >> 1), &V_lds[b][wi * 512]);
    }
  };

  for (int ph = 0; ph < 2; ++ph) {
    const int qt = ph ? bx : (31 - bx);
    const int q0 = qt * 64;
    const int qrow_lo = q0 + wv * 16;
    const int crow = qrow_lo + l4 * 4;

    bf16x8 qf[4];
    {
      const unsigned short* qp = q_int + ((size_t)(qrow_lo + l15) * NH + h) * HD + l4 * 8;
#pragma unroll
      for (int kd = 0; kd < 4; ++kd) qf[kd] = *(const bf16x8*)(qp + kd * 32);
    }
    float qsS[4];
#pragma unroll
    for (int r = 0; r < 4; ++r) qsS[r] = ATT_SCALE * q_ds[(size_t)(crow + r) * NH + h];

    float m_run[4], l_run[4];
    f32x4 o_acc[8] = {};
#pragma unroll
    for (int r = 0; r < 4; ++r) { m_run[r] = -3.0e38f; l_run[r] = 0.f; }

    const int nkt = qt + 1;
    stage(0, 0);
    __syncthreads();

    for (int kt = 0; kt < nkt; ++kt) {
      const int cur = kt & 1;
      float ksd[4];
#pragma unroll
      for (int nt = 0; nt < 4; ++nt)
        ksd[nt] = k_ds[(size_t)(kt * 64 + nt * 16 + l15) * NKV + kvh];
      if (kt + 1 < nkt) stage(cur ^ 1, kt + 1);

      f32x4 sacc[4] = {};
#pragma unroll
      for (int nt = 0; nt < 4; ++nt) {
        int key = nt * 16 + l15;
#pragma unroll
        for (int kd = 0; kd < 4; ++kd) {
          int byte = key * 256 + kd * 64 + l4 * 16;
          byte ^= (key & 7) << 4;
          bf16x8 kf = *(const bf16x8*)((const char*)&K_lds[cur][0] + byte);
          sacc[nt] = __builtin_amdgcn_mfma_f32_16x16x32_bf16(qf[kd], kf, sacc[nt], 0, 0, 0);
        }
      }

      float p[4][4];
      float tmax[4] = {-3.0e38f, -3.0e38f, -3.0e38f, -3.0e38f};
#pragma unroll
      for (int nt = 0; nt < 4; ++nt) {
        int keyg = kt * 64 + nt * 16 + l15;
#pragma unroll
        for (int r = 0; r < 4; ++r) {
          float sc = sacc[nt][r] * (qsS[r] * ksd[nt]);
          sc = (keyg <= crow + r) ? sc : -3.0e38f;
          p[nt][r] = sc;
          tmax[r] = fmaxf(tmax[r], sc);
        }
      }
#pragma unroll
      for (int m = 1; m < 16; m <<= 1)
#pragma unroll
        for (int r = 0; r < 4; ++r) tmax[r] = fmaxf(tmax[r], __shfl_xor(tmax[r], m));
      float corr[4], psum[4];
#pragma unroll
      for (int r = 0; r < 4; ++r) {
        float mnew = fmaxf(m_run[r], tmax[r]);
        corr[r] = __expf(m_run[r] - mnew);
        m_run[r] = mnew;
        l_run[r] *= corr[r];
        psum[r] = 0.f;
      }
#pragma unroll
      for (int nt = 0; nt < 4; ++nt)
#pragma unroll
        for (int r = 0; r < 4; ++r) {
          float e = __expf(p[nt][r] - m_run[r]);
          p[nt][r] = e;
          psum[r] += e;
        }
#pragma unroll
      for (int m = 1; m < 16; m <<= 1)
#pragma unroll
        for (int r = 0; r < 4; ++r) psum[r] += __shfl_xor(psum[r], m);
#pragma unroll
      for (int r = 0; r < 4; ++r) l_run[r] += psum[r];
#pragma unroll
      for (int dt = 0; dt < 8; ++dt)
#pragma unroll
        for (int r = 0; r < 4; ++r) o_acc[dt][r] *= corr[r];

#pragma unroll
      for (int nt = 0; nt < 4; ++nt)
#pragma unroll
        for (int r = 0; r < 4; ++r)
          P_lds[wv][(l4 * 4 + r) * 72 + nt * 16 + l15] = f2b(p[nt][r]);

      bf16x8 pa[2];
#pragma unroll
      for (int kc = 0; kc < 2; ++kc)
        pa[kc] = *(const bf16x8*)((const char*)&P_lds[wv][0] + l15 * 144 + kc * 64 + l4 * 16);

#pragma unroll
      for (int dt = 0; dt < 8; ++dt) {
        int d = dt * 16 + l15;
        int swzv = (d & 7) << 4;
#pragma unroll
        for (int kc = 0; kc < 2; ++kc) {
          int byte = d * 128 + ((kc * 64 + l4 * 16) ^ swzv);
          bf16x8 vb = *(const bf16x8*)((const char*)&V_lds[cur][0] + byte);
          o_acc[dt] = __builtin_amdgcn_mfma_f32_16x16x32_bf16(pa[kc], vb, o_acc[dt], 0, 0, 0);
        }
      }
      __syncthreads();
    }

    float inv_l[4];
#pragma unroll
    for (int r = 0; r < 4; ++r) inv_l[r] = 1.0f / l_run[r];
#pragma unroll
    for (int dt = 0; dt < 8; ++dt)
#pragma unroll
      for (int r = 0; r < 4; ++r)
        o_bf[(size_t)(crow + r) * (NH * HD) + h * HD + dt * 16 + l15] = f2b(o_acc[dt][r] * inv_l[r]);
  }
}

extern "C" void kernel_launch(void* const* d_in, const int* in_sizes, int n_in,
                              void* d_out, int out_size, void* d_ws, size_t ws_size,
                              hipStream_t stream) {
  const float* x    = (const float*)d_in[0];
  const float* Wq   = (const float*)d_in[1];
  const float* Wk   = (const float*)d_in[2];
  const float* Wv   = (const float*)d_in[3];
  const float* Wo   = (const float*)d_in[4];
  const float* cost = (const float*)d_in[5];
  const float* sint = (const float*)d_in[6];
  float* out = (float*)d_out;
  char* ws = (char*)d_ws;

  unsigned short* xb     = (unsigned short*)(ws);                 // 16 MB (dead after gemm1)
  unsigned short* wqkv_t = (unsigned short*)(ws + 16777216);      // 48 MB (6144x4096)
  unsigned short* wo_t   = (unsigned short*)(ws + 67108864);      // 32 MB (4096x4096)
  float*          qkv    = (float*)(ws + 100663296);              // 48 MB (2048x6144)
  unsigned short* q_int  = (unsigned short*)(ws + 150994944);     // 16 MB
  unsigned short* k_int  = (unsigned short*)(ws + 167772160);     // 4 MB
  unsigned short* v_bf   = (unsigned short*)(ws + 171966464);     // 4 MB
  float*          q_ds   = (float*)(ws + 176160768);              // 256 KB
  float*          k_ds   = (float*)(ws + 176422912);              // 64 KB
  unsigned short* o_bf   = (unsigned short*)(ws + 176488448);     // 16 MB
  unsigned short* v_t    = (unsigned short*)(ws);                 // 4 MB, aliases dead xb... (alias only after gemm1)

  hipFuncSetAttribute((const void*)k_gemm256,
                      hipFuncAttributeMaxDynamicSharedMemorySize, 131072);

  k_cvt_x<<<(S_LEN * DMODEL / 4) / 256, 256, 0, stream>>>(x, xb);
  k_transpose<<<dim3(64, 64), 256, 0, stream>>>(Wq, wqkv_t, 4096, 4096);
  k_transpose<<<dim3(64, 16), 256, 0, stream>>>(Wk, wqkv_t + (size_t)4096 * 4096, 4096, 1024);
  k_transpose<<<dim3(64, 16), 256, 0, stream>>>(Wv, wqkv_t + (size_t)5120 * 4096, 4096, 1024);
  k_transpose<<<dim3(64, 64), 256, 0, stream>>>(Wo, wo_t, 4096, 4096);
  k_gemm256<<<dim3(192), 512, 131072, stream>>>(xb, wqkv_t, qkv, 2048, 6144, 4096);
  k_ropequant<<<dim3(2048, 12), 256, 0, stream>>>(qkv, cost, sint, q_int, q_ds, k_int, k_ds, v_bf);
  k_vt<<<dim3(32, 2, 8), 256, 0, stream>>>(v_bf, v_t);
  k_attn<<<dim3(512), 256, 0, stream>>>(q_int, q_ds, k_int, k_ds, v_t, o_bf);
  k_gemm256<<<dim3(128), 512, 131072, stream>>>(o_bf, wo_t, out, 2048, 4096, 4096);
}

// Round 5
// 382.106 us; speedup vs baseline: 1.1405x; 1.1405x over previous
//
#include <hip/hip_runtime.h>
#include <hip/hip_bf16.h>

#define S_LEN 2048
#define DMODEL 4096
#define NH 32
#define NKV 8
#define HD 128
#define NQKV 6144
#define ATT_SCALE 0.08838834764831845f  // 1/sqrt(128)

typedef __bf16 bf16x8 __attribute__((ext_vector_type(8)));
typedef float f32x4 __attribute__((ext_vector_type(4)));

// float -> bf16 bits, round-to-nearest-even
__device__ __forceinline__ unsigned short f2b(float f) {
  union { float f; unsigned u; } a; a.f = f;
  unsigned u = a.u;
  return (unsigned short)((u + 0x7FFFu + ((u >> 16) & 1u)) >> 16);
}

__device__ __forceinline__ void gl16(const unsigned short* g, unsigned short* l) {
  __builtin_amdgcn_global_load_lds(
      (const __attribute__((address_space(1))) unsigned int*)g,
      (__attribute__((address_space(3))) unsigned int*)l, 16, 0, 0);
}

// ---------------- x fp32 -> bf16 ----------------
__global__ __launch_bounds__(256) void k_cvt_x(const float* __restrict__ x,
                                               unsigned short* __restrict__ xb) {
  int i = blockIdx.x * 256 + threadIdx.x;
  float4 v = ((const float4*)x)[i];
  ushort4 o;
  o.x = f2b(v.x); o.y = f2b(v.y); o.z = f2b(v.z); o.w = f2b(v.w);
  ((ushort4*)xb)[i] = o;
}

// ------------- W (K,N) fp32 -> Wt (N,K) bf16 -------------
__global__ __launch_bounds__(256) void k_transpose(const float* __restrict__ W,
                                                   unsigned short* __restrict__ Wt,
                                                   int K, int N) {
  __shared__ float tile[64][65];
  int k0 = blockIdx.x * 64, n0 = blockIdx.y * 64;
  int tx = threadIdx.x & 31, ty = threadIdx.x >> 5;
#pragma unroll
  for (int i = 0; i < 8; ++i) {
    int k = ty + i * 8;
    const float* src = W + (size_t)(k0 + k) * N + n0;
    tile[k][tx] = src[tx];
    tile[k][tx + 32] = src[tx + 32];
  }
  __syncthreads();
#pragma unroll
  for (int i = 0; i < 8; ++i) {
    int n = ty + i * 8;
    unsigned short* dst = Wt + (size_t)(n0 + n) * K + k0;
    dst[tx] = f2b(tile[tx][n]);
    dst[tx + 32] = f2b(tile[tx + 32][n]);
  }
}

// ------------- V [S][NKV][HD] bf16 -> V^T [NKV][HD][S] bf16 -------------
__global__ __launch_bounds__(256) void k_vt(const unsigned short* __restrict__ v_bf,
                                            unsigned short* __restrict__ v_t) {
  __shared__ unsigned short tile[64][65];
  int s0 = blockIdx.x * 64, d0 = blockIdx.y * 64, kvh = blockIdx.z;
  int tx = threadIdx.x & 63, ty = threadIdx.x >> 6;
#pragma unroll
  for (int i = 0; i < 16; ++i) {
    int s = ty + i * 4;
    tile[s][tx] = v_bf[((size_t)(s0 + s) * NKV + kvh) * HD + d0 + tx];
  }
  __syncthreads();
#pragma unroll
  for (int i = 0; i < 16; ++i) {
    int d = ty + i * 4;
    v_t[((size_t)kvh * HD + d0 + d) * S_LEN + s0 + tx] = tile[tx][d];
  }
}

// ---------------- out = p0 + p1 (split-K fixup) ----------------
__global__ __launch_bounds__(256) void k_sum2(const float* __restrict__ p0,
                                              const float* __restrict__ p1,
                                              float* __restrict__ out) {
  int i = blockIdx.x * 256 + threadIdx.x;
  float4 a = ((const float4*)p0)[i];
  float4 b = ((const float4*)p1)[i];
  float4 o;
  o.x = a.x + b.x; o.y = a.y + b.y; o.z = a.z + b.z; o.w = a.w + b.w;
  ((float4*)out)[i] = o;
}

// ============ 256x256 8-phase GEMM (+ optional in-grid split-K) ============
// BM=BN=256, BK=64, 512 threads = 8 waves (2Mx4N). LDS 128 KB dynamic.
// G4 XOR swizzle byte ^= ((row&7)<<4): applied via pre-swizzled gl16 SOURCE k-slot
// + swizzled ds_read column. Counted vmcnt(6) once per K-tile; raw s_barrier; setprio.
// Grid = mtiles*ntiles*splits (splits = K/kchunk); split s writes C + s*M*N.
__global__ __launch_bounds__(512, 2) void k_gemm256(const unsigned short* __restrict__ A,
                                                    const unsigned short* __restrict__ B,
                                                    float* __restrict__ C,
                                                    int M, int N, int K, int kchunk) {
  extern __shared__ __align__(16) unsigned short smem[];
  char* Sc = (char*)smem;
  const int tid = threadIdx.x;
  const int wvid = tid >> 6, l = tid & 63;
  const int wm = wvid >> 2, wn = wvid & 3;
  const int l15 = l & 15, l4 = l >> 4;

  // XCD-bijective swizzle (grid % 8 == 0 at all call sites)
  const int nwg = gridDim.x;
  const int cpx = nwg >> 3;
  const int bid = blockIdx.x;
  const int swz = (bid & 7) * cpx + (bid >> 3);
  const int mtiles = M >> 8;
  const int ntiles = N >> 8;
  const int sidx = swz / (mtiles * ntiles);
  const int rem = swz % (mtiles * ntiles);
  const int m0 = (rem % mtiles) * 256;
  const int n0 = (rem / mtiles) * 256;

  const unsigned short* Ab_g = A + (size_t)sidx * kchunk;
  const unsigned short* Bb_g = B + (size_t)sidx * kchunk;
  float* Cb = C + (size_t)sidx * M * N;
  const int NT = kchunk >> 6;

  // read-side: row&7 == l15&7 for every fragment row (wm*64, fn*16 are mult of 8... 16)
  const int rsw = (l15 & 7) << 4;
  const int a_base = (wm * 64 + l15) * 128;   // + fm*2048 + ((ks*64 + l4*16) ^ rsw)
  const int b_base = (wn * 32 + l15) * 128;
  const int c0 = (l4 * 16) ^ rsw;             // ks=0 column byte
  const int c1 = (64 + l4 * 16) ^ rsw;        // ks=1 column byte

  // stage-side: dest (row = blk*8 + l>>3, slot = l&7) <- global k8 = (l&7)^(l>>3)
  const int st_row = l >> 3;
  const int st_k8 = (l & 7) ^ st_row;

  auto stA = [&](int tt, int h) {
    if (tt >= NT) return;
    const unsigned short* g = Ab_g + (size_t)(m0 + h * 128) * K + tt * 64 + st_k8 * 8;
    unsigned short* lb = (unsigned short*)(Sc + (tt & 1) * 32768 + h * 16384);
#pragma unroll
    for (int j = 0; j < 2; ++j) {
      int blk = j * 8 + wvid;
      gl16(g + (size_t)(blk * 8 + st_row) * K, lb + blk * 512);
    }
  };
  auto stB = [&](int tt, int c) {
    if (tt >= NT) return;
    const unsigned short* g = Bb_g + (size_t)(n0 + c * 128) * K + tt * 64 + st_k8 * 8;
    unsigned short* lb = (unsigned short*)(Sc + 65536 + (tt & 1) * 32768 + c * 16384);
#pragma unroll
    for (int j = 0; j < 2; ++j) {
      int blk = j * 8 + wvid;
      gl16(g + (size_t)(blk * 8 + st_row) * K, lb + blk * 512);
    }
  };

  f32x4 acc[2][4][2][2] = {};

  // ---- prologue: steady-state issue order A0,B1,A1 | B0(t) ----
  stA(0, 0); stB(0, 1); stA(0, 1); stB(0, 0);
  stA(1, 0); stB(1, 1); stA(1, 1);
  if (NT > 1) asm volatile("s_waitcnt vmcnt(6)" ::: "memory");
  else        asm volatile("s_waitcnt vmcnt(0)" ::: "memory");
  __builtin_amdgcn_s_barrier();

  for (int t = 0; t < NT; ++t) {
    const int b = t & 1;
    const char* Ab = Sc + b * 32768;
    const char* Bb = Sc + 65536 + b * 32768;
    bf16x8 a[4][2], bb[2][2];

    // ===== phase 1: (h0,c0) — read A-h0(8) + B-h0(4); stage B0(t+1) =====
#pragma unroll
    for (int fm = 0; fm < 4; ++fm) {
      a[fm][0] = *(const bf16x8*)(Ab + a_base + fm * 2048 + c0);
      a[fm][1] = *(const bf16x8*)(Ab + a_base + fm * 2048 + c1);
    }
#pragma unroll
    for (int fn = 0; fn < 2; ++fn) {
      bb[fn][0] = *(const bf16x8*)(Bb + b_base + fn * 2048 + c0);
      bb[fn][1] = *(const bf16x8*)(Bb + b_base + fn * 2048 + c1);
    }
    stB(t + 1, 0);
    __builtin_amdgcn_s_barrier();
    __builtin_amdgcn_s_setprio(1);
#pragma unroll
    for (int fm = 0; fm < 4; ++fm)
#pragma unroll
      for (int fn = 0; fn < 2; ++fn)
#pragma unroll
        for (int ks = 0; ks < 2; ++ks)
          acc[0][fm][0][fn] = __builtin_amdgcn_mfma_f32_16x16x32_bf16(a[fm][ks], bb[fn][ks], acc[0][fm][0][fn], 0, 0, 0);
    __builtin_amdgcn_s_setprio(0);
    __builtin_amdgcn_s_barrier();

    // ===== phase 2: (h0,c1) — read B-h1(4); stage A0(t+2) =====
#pragma unroll
    for (int fn = 0; fn < 2; ++fn) {
      bb[fn][0] = *(const bf16x8*)(Bb + 16384 + b_base + fn * 2048 + c0);
      bb[fn][1] = *(const bf16x8*)(Bb + 16384 + b_base + fn * 2048 + c1);
    }
    stA(t + 2, 0);
    __builtin_amdgcn_s_barrier();
    __builtin_amdgcn_s_setprio(1);
#pragma unroll
    for (int fm = 0; fm < 4; ++fm)
#pragma unroll
      for (int fn = 0; fn < 2; ++fn)
#pragma unroll
        for (int ks = 0; ks < 2; ++ks)
          acc[0][fm][1][fn] = __builtin_amdgcn_mfma_f32_16x16x32_bf16(a[fm][ks], bb[fn][ks], acc[0][fm][1][fn], 0, 0, 0);
    __builtin_amdgcn_s_setprio(0);
    __builtin_amdgcn_s_barrier();

    // ===== phase 3: (h1,c1) — read A-h1(8); stage B1(t+2); B-h1 held in regs =====
#pragma unroll
    for (int fm = 0; fm < 4; ++fm) {
      a[fm][0] = *(const bf16x8*)(Ab + 16384 + a_base + fm * 2048 + c0);
      a[fm][1] = *(const bf16x8*)(Ab + 16384 + a_base + fm * 2048 + c1);
    }
    stB(t + 2, 1);
    __builtin_amdgcn_s_barrier();
    __builtin_amdgcn_s_setprio(1);
#pragma unroll
    for (int fm = 0; fm < 4; ++fm)
#pragma unroll
      for (int fn = 0; fn < 2; ++fn)
#pragma unroll
        for (int ks = 0; ks < 2; ++ks)
          acc[1][fm][1][fn] = __builtin_amdgcn_mfma_f32_16x16x32_bf16(a[fm][ks], bb[fn][ks], acc[1][fm][1][fn], 0, 0, 0);
    __builtin_amdgcn_s_setprio(0);
    __builtin_amdgcn_s_barrier();

    // ===== phase 4: (h1,c0) — read B-h0(4); stage A1(t+2); boundary vmcnt =====
#pragma unroll
    for (int fn = 0; fn < 2; ++fn) {
      bb[fn][0] = *(const bf16x8*)(Bb + b_base + fn * 2048 + c0);
      bb[fn][1] = *(const bf16x8*)(Bb + b_base + fn * 2048 + c1);
    }
    stA(t + 2, 1);
    __builtin_amdgcn_s_barrier();
    __builtin_amdgcn_s_setprio(1);
#pragma unroll
    for (int fm = 0; fm < 4; ++fm)
#pragma unroll
      for (int fn = 0; fn < 2; ++fn)
#pragma unroll
        for (int ks = 0; ks < 2; ++ks)
          acc[1][fm][0][fn] = __builtin_amdgcn_mfma_f32_16x16x32_bf16(a[fm][ks], bb[fn][ks], acc[1][fm][0][fn], 0, 0, 0);
    __builtin_amdgcn_s_setprio(0);
    if (t + 1 < NT) {
      if (t + 1 == NT - 1) asm volatile("s_waitcnt vmcnt(0)" ::: "memory");
      else                 asm volatile("s_waitcnt vmcnt(6)" ::: "memory");
    }
    __builtin_amdgcn_s_barrier();
  }

  // ---- epilogue: C write ----
#pragma unroll
  for (int h = 0; h < 2; ++h)
#pragma unroll
    for (int fm = 0; fm < 4; ++fm) {
      int row0 = m0 + h * 128 + wm * 64 + fm * 16 + l4 * 4;
#pragma unroll
      for (int c = 0; c < 2; ++c)
#pragma unroll
        for (int fn = 0; fn < 2; ++fn) {
          int col = n0 + c * 128 + wn * 32 + fn * 16 + l15;
#pragma unroll
          for (int r = 0; r < 4; ++r)
            Cb[(size_t)(row0 + r) * N + col] = acc[h][fm][c][fn][r];
        }
    }
}

// ------------- RoPE + int8 quantize (stored as bf16 ints) -------------
__global__ __launch_bounds__(256) void k_ropequant(const float* __restrict__ qkv,
                                                   const float* __restrict__ cost,
                                                   const float* __restrict__ sint,
                                                   unsigned short* __restrict__ q_int,
                                                   float* __restrict__ q_ds,
                                                   unsigned short* __restrict__ k_int,
                                                   float* __restrict__ k_ds,
                                                   unsigned short* __restrict__ v_bf) {
  int s = blockIdx.x;
  int wv = threadIdx.x >> 6, l = threadIdx.x & 63;
  int hh = blockIdx.y * 4 + wv;  // 0..47: [0,32) q, [32,40) k, [40,48) v
  const float* row = qkv + (size_t)s * NQKV;
  if (hh < NH + NKV) {
    int off = (hh < NH) ? hh * HD : DMODEL + (hh - NH) * HD;
    float t1 = row[off + l], t2 = row[off + 64 + l];
    float c1 = cost[s * HD + l],      sn1 = sint[s * HD + l];
    float c2 = cost[s * HD + 64 + l], sn2 = sint[s * HD + 64 + l];
    float o1 = t1 * c1 - t2 * sn1;
    float o2 = t2 * c2 + t1 * sn2;
    float amax = fmaxf(fabsf(o1), fabsf(o2));
#pragma unroll
    for (int m = 1; m < 64; m <<= 1) amax = fmaxf(amax, __shfl_xor(amax, m));
    amax = fmaxf(amax, 1e-5f);
    float scale = 127.0f / amax;
    float dscale = amax * (1.0f / 127.0f);
    float v1 = fminf(fmaxf(rintf(o1 * scale), -128.f), 127.f);
    float v2 = fminf(fmaxf(rintf(o2 * scale), -128.f), 127.f);
    if (hh < NH) {
      unsigned short* dst = q_int + ((size_t)s * NH + hh) * HD;
      dst[l] = f2b(v1); dst[l + 64] = f2b(v2);
      if (l == 0) q_ds[(size_t)s * NH + hh] = dscale;
    } else {
      int kh = hh - NH;
      unsigned short* dst = k_int + ((size_t)s * NKV + kh) * HD;
      dst[l] = f2b(v1); dst[l + 64] = f2b(v2);
      if (l == 0) k_ds[(size_t)s * NKV + kh] = dscale;
    }
  } else {
    int vh = hh - (NH + NKV);
    const float* src = row + DMODEL + NKV * HD + vh * HD;
    unsigned short* dst = v_bf + ((size_t)s * NKV + vh) * HD;
    dst[l] = f2b(src[l]);
    dst[l + 64] = f2b(src[l + 64]);
  }
}

// ------------- causal GQA flash attention, paired q-tiles, async dbuf staging -------------
__global__ __launch_bounds__(256) void k_attn(const unsigned short* __restrict__ q_int,
                                              const float* __restrict__ q_ds,
                                              const unsigned short* __restrict__ k_int,
                                              const float* __restrict__ k_ds,
                                              const unsigned short* __restrict__ v_t,
                                              unsigned short* __restrict__ o_bf) {
  __shared__ __align__(16) unsigned short K_lds[2][8192];
  __shared__ __align__(16) unsigned short V_lds[2][8192];
  __shared__ __align__(16) unsigned short P_lds[4][16 * 72];

  const int bid = blockIdx.x;
  const int kvh = bid & 7;
  const int h = kvh * 4 + ((bid >> 3) & 3);
  const int bx = bid >> 5;
  const int tid = threadIdx.x, wv = tid >> 6, l = tid & 63;
  const int l15 = l & 15, l4 = l >> 4;

  auto stage = [&](int b, int kt) {
    const unsigned short* kB = k_int + (size_t)kt * 64 * (NKV * HD) + kvh * HD;
    const unsigned short* vB = v_t + (size_t)kvh * HD * S_LEN + (size_t)kt * 64;
#pragma unroll
    for (int j = 0; j < 4; ++j) {
      int wi = j * 4 + wv;
      int slot = wi * 64 + l;
      int key = slot >> 4;
      int colb = ((slot & 15) * 16) ^ ((key & 7) << 4);
      gl16(kB + key * (NKV * HD) + (colb >> 1), &K_lds[b][wi * 512]);
      int d = slot >> 3;
      int ckb = ((slot & 7) * 16) ^ ((d & 7) << 4);
      gl16(vB + (size_t)d * S_LEN + (ckb >> 1), &V_lds[b][wi * 512]);
    }
  };

  for (int ph = 0; ph < 2; ++ph) {
    const int qt = ph ? bx : (31 - bx);
    const int q0 = qt * 64;
    const int qrow_lo = q0 + wv * 16;
    const int crow = qrow_lo + l4 * 4;

    bf16x8 qf[4];
    {
      const unsigned short* qp = q_int + ((size_t)(qrow_lo + l15) * NH + h) * HD + l4 * 8;
#pragma unroll
      for (int kd = 0; kd < 4; ++kd) qf[kd] = *(const bf16x8*)(qp + kd * 32);
    }
    float qsS[4];
#pragma unroll
    for (int r = 0; r < 4; ++r) qsS[r] = ATT_SCALE * q_ds[(size_t)(crow + r) * NH + h];

    float m_run[4], l_run[4];
    f32x4 o_acc[8] = {};
#pragma unroll
    for (int r = 0; r < 4; ++r) { m_run[r] = -3.0e38f; l_run[r] = 0.f; }

    const int nkt = qt + 1;
    stage(0, 0);
    __syncthreads();

    for (int kt = 0; kt < nkt; ++kt) {
      const int cur = kt & 1;
      float ksd[4];
#pragma unroll
      for (int nt = 0; nt < 4; ++nt)
        ksd[nt] = k_ds[(size_t)(kt * 64 + nt * 16 + l15) * NKV + kvh];
      if (kt + 1 < nkt) stage(cur ^ 1, kt + 1);

      f32x4 sacc[4] = {};
#pragma unroll
      for (int nt = 0; nt < 4; ++nt) {
        int key = nt * 16 + l15;
#pragma unroll
        for (int kd = 0; kd < 4; ++kd) {
          int byte = key * 256 + kd * 64 + l4 * 16;
          byte ^= (key & 7) << 4;
          bf16x8 kf = *(const bf16x8*)((const char*)&K_lds[cur][0] + byte);
          sacc[nt] = __builtin_amdgcn_mfma_f32_16x16x32_bf16(qf[kd], kf, sacc[nt], 0, 0, 0);
        }
      }

      float p[4][4];
      float tmax[4] = {-3.0e38f, -3.0e38f, -3.0e38f, -3.0e38f};
#pragma unroll
      for (int nt = 0; nt < 4; ++nt) {
        int keyg = kt * 64 + nt * 16 + l15;
#pragma unroll
        for (int r = 0; r < 4; ++r) {
          float sc = sacc[nt][r] * (qsS[r] * ksd[nt]);
          sc = (keyg <= crow + r) ? sc : -3.0e38f;
          p[nt][r] = sc;
          tmax[r] = fmaxf(tmax[r], sc);
        }
      }
#pragma unroll
      for (int m = 1; m < 16; m <<= 1)
#pragma unroll
        for (int r = 0; r < 4; ++r) tmax[r] = fmaxf(tmax[r], __shfl_xor(tmax[r], m));
      float corr[4], psum[4];
#pragma unroll
      for (int r = 0; r < 4; ++r) {
        float mnew = fmaxf(m_run[r], tmax[r]);
        corr[r] = __expf(m_run[r] - mnew);
        m_run[r] = mnew;
        l_run[r] *= corr[r];
        psum[r] = 0.f;
      }
#pragma unroll
      for (int nt = 0; nt < 4; ++nt)
#pragma unroll
        for (int r = 0; r < 4; ++r) {
          float e = __expf(p[nt][r] - m_run[r]);
          p[nt][r] = e;
          psum[r] += e;
        }
#pragma unroll
      for (int m = 1; m < 16; m <<= 1)
#pragma unroll
        for (int r = 0; r < 4; ++r) psum[r] += __shfl_xor(psum[r], m);
#pragma unroll
      for (int r = 0; r < 4; ++r) l_run[r] += psum[r];
#pragma unroll
      for (int dt = 0; dt < 8; ++dt)
#pragma unroll
        for (int r = 0; r < 4; ++r) o_acc[dt][r] *= corr[r];

#pragma unroll
      for (int nt = 0; nt < 4; ++nt)
#pragma unroll
        for (int r = 0; r < 4; ++r)
          P_lds[wv][(l4 * 4 + r) * 72 + nt * 16 + l15] = f2b(p[nt][r]);

      bf16x8 pa[2];
#pragma unroll
      for (int kc = 0; kc < 2; ++kc)
        pa[kc] = *(const bf16x8*)((const char*)&P_lds[wv][0] + l15 * 144 + kc * 64 + l4 * 16);

#pragma unroll
      for (int dt = 0; dt < 8; ++dt) {
        int d = dt * 16 + l15;
        int swzv = (d & 7) << 4;
#pragma unroll
        for (int kc = 0; kc < 2; ++kc) {
          int byte = d * 128 + ((kc * 64 + l4 * 16) ^ swzv);
          bf16x8 vb = *(const bf16x8*)((const char*)&V_lds[cur][0] + byte);
          o_acc[dt] = __builtin_amdgcn_mfma_f32_16x16x32_bf16(pa[kc], vb, o_acc[dt], 0, 0, 0);
        }
      }
      __syncthreads();
    }

    float inv_l[4];
#pragma unroll
    for (int r = 0; r < 4; ++r) inv_l[r] = 1.0f / l_run[r];
#pragma unroll
    for (int dt = 0; dt < 8; ++dt)
#pragma unroll
      for (int r = 0; r < 4; ++r)
        o_bf[(size_t)(crow + r) * (NH * HD) + h * HD + dt * 16 + l15] = f2b(o_acc[dt][r] * inv_l[r]);
  }
}

extern "C" void kernel_launch(void* const* d_in, const int* in_sizes, int n_in,
                              void* d_out, int out_size, void* d_ws, size_t ws_size,
                              hipStream_t stream) {
  const float* x    = (const float*)d_in[0];
  const float* Wq   = (const float*)d_in[1];
  const float* Wk   = (const float*)d_in[2];
  const float* Wv   = (const float*)d_in[3];
  const float* Wo   = (const float*)d_in[4];
  const float* cost = (const float*)d_in[5];
  const float* sint = (const float*)d_in[6];
  float* out = (float*)d_out;
  char* ws = (char*)d_ws;

  unsigned short* xb     = (unsigned short*)(ws);                 // 16 MB (dead after gemm1)
  unsigned short* wqkv_t = (unsigned short*)(ws + 16777216);      // 48 MB (dead after gemm1)
  unsigned short* wo_t   = (unsigned short*)(ws + 67108864);      // 32 MB (4096x4096)
  float*          qkv    = (float*)(ws + 100663296);              // 48 MB (dead after ropequant)
  unsigned short* q_int  = (unsigned short*)(ws + 150994944);     // 16 MB
  unsigned short* k_int  = (unsigned short*)(ws + 167772160);     // 4 MB
  unsigned short* v_bf   = (unsigned short*)(ws + 171966464);     // 4 MB
  float*          q_ds   = (float*)(ws + 176160768);              // 256 KB
  float*          k_ds   = (float*)(ws + 176422912);              // 64 KB
  unsigned short* o_bf   = (unsigned short*)(ws + 176488448);     // 16 MB
  unsigned short* v_t    = (unsigned short*)(ws);                 // 4 MB, aliases dead xb
  float*          part   = (float*)(ws + 16777216);               // 64 MB split-K partials,
                                                                  // aliases dead wqkv_t+qkv

  hipFuncSetAttribute((const void*)k_gemm256,
                      hipFuncAttributeMaxDynamicSharedMemorySize, 131072);

  k_cvt_x<<<(S_LEN * DMODEL / 4) / 256, 256, 0, stream>>>(x, xb);
  k_transpose<<<dim3(64, 64), 256, 0, stream>>>(Wq, wqkv_t, 4096, 4096);
  k_transpose<<<dim3(64, 16), 256, 0, stream>>>(Wk, wqkv_t + (size_t)4096 * 4096, 4096, 1024);
  k_transpose<<<dim3(64, 16), 256, 0, stream>>>(Wv, wqkv_t + (size_t)5120 * 4096, 4096, 1024);
  k_transpose<<<dim3(64, 64), 256, 0, stream>>>(Wo, wo_t, 4096, 4096);
  k_gemm256<<<dim3(192), 512, 131072, stream>>>(xb, wqkv_t, qkv, 2048, 6144, 4096, 4096);
  k_ropequant<<<dim3(2048, 12), 256, 0, stream>>>(qkv, cost, sint, q_int, q_ds, k_int, k_ds, v_bf);
  k_vt<<<dim3(32, 2, 8), 256, 0, stream>>>(v_bf, v_t);
  k_attn<<<dim3(512), 256, 0, stream>>>(q_int, q_ds, k_int, k_ds, v_t, o_bf);
  // out-proj: split-K x2 -> 256 blocks (full CU fill), then fixup sum
  k_gemm256<<<dim3(256), 512, 131072, stream>>>(o_bf, wo_t, part, 2048, 4096, 4096, 2048);
  k_sum2<<<dim3(8192), 256, 0, stream>>>(part, part + (size_t)2048 * 4096, out);
}

// Round 6
// 361.232 us; speedup vs baseline: 1.2065x; 1.0578x over previous
//
#include <hip/hip_runtime.h>
#include <hip/hip_bf16.h>

#define S_LEN 2048
#define DMODEL 4096
#define NH 32
#define NKV 8
#define HD 128
#define NQKV 6144
#define ATT_SCALE 0.08838834764831845f  // 1/sqrt(128)

typedef __bf16 bf16x8 __attribute__((ext_vector_type(8)));
typedef float f32x4 __attribute__((ext_vector_type(4)));

// float -> bf16 bits, round-to-nearest-even
__device__ __forceinline__ unsigned short f2b(float f) {
  union { float f; unsigned u; } a; a.f = f;
  unsigned u = a.u;
  return (unsigned short)((u + 0x7FFFu + ((u >> 16) & 1u)) >> 16);
}

__device__ __forceinline__ void gl16(const unsigned short* g, unsigned short* l) {
  __builtin_amdgcn_global_load_lds(
      (const __attribute__((address_space(1))) unsigned int*)g,
      (__attribute__((address_space(3))) unsigned int*)l, 16, 0, 0);
}

// ---------------- x fp32 -> bf16 ----------------
__global__ __launch_bounds__(256) void k_cvt_x(const float* __restrict__ x,
                                               unsigned short* __restrict__ xb) {
  int i = blockIdx.x * 256 + threadIdx.x;
  float4 v = ((const float4*)x)[i];
  ushort4 o;
  o.x = f2b(v.x); o.y = f2b(v.y); o.z = f2b(v.z); o.w = f2b(v.w);
  ((ushort4*)xb)[i] = o;
}

// ------------- W (K,N) fp32 -> Wt (N,K) bf16 -------------
__global__ __launch_bounds__(256) void k_transpose(const float* __restrict__ W,
                                                   unsigned short* __restrict__ Wt,
                                                   int K, int N) {
  __shared__ float tile[64][65];
  int k0 = blockIdx.x * 64, n0 = blockIdx.y * 64;
  int tx = threadIdx.x & 31, ty = threadIdx.x >> 5;
#pragma unroll
  for (int i = 0; i < 8; ++i) {
    int k = ty + i * 8;
    const float* src = W + (size_t)(k0 + k) * N + n0;
    tile[k][tx] = src[tx];
    tile[k][tx + 32] = src[tx + 32];
  }
  __syncthreads();
#pragma unroll
  for (int i = 0; i < 8; ++i) {
    int n = ty + i * 8;
    unsigned short* dst = Wt + (size_t)(n0 + n) * K + k0;
    dst[tx] = f2b(tile[tx][n]);
    dst[tx + 32] = f2b(tile[tx + 32][n]);
  }
}

// ------------- V [S][NKV][HD] bf16 -> V^T [NKV][HD][S] bf16 -------------
__global__ __launch_bounds__(256) void k_vt(const unsigned short* __restrict__ v_bf,
                                            unsigned short* __restrict__ v_t) {
  __shared__ unsigned short tile[64][65];
  int s0 = blockIdx.x * 64, d0 = blockIdx.y * 64, kvh = blockIdx.z;
  int tx = threadIdx.x & 63, ty = threadIdx.x >> 6;
#pragma unroll
  for (int i = 0; i < 16; ++i) {
    int s = ty + i * 4;
    tile[s][tx] = v_bf[((size_t)(s0 + s) * NKV + kvh) * HD + d0 + tx];
  }
  __syncthreads();
#pragma unroll
  for (int i = 0; i < 16; ++i) {
    int d = ty + i * 4;
    v_t[((size_t)kvh * HD + d0 + d) * S_LEN + s0 + tx] = tile[tx][d];
  }
}

// ---------------- out = p0 + p1 (split-K fixup) ----------------
__global__ __launch_bounds__(256) void k_sum2(const float* __restrict__ p0,
                                              const float* __restrict__ p1,
                                              float* __restrict__ out) {
  int i = blockIdx.x * 256 + threadIdx.x;
  float4 a = ((const float4*)p0)[i];
  float4 b = ((const float4*)p1)[i];
  float4 o;
  o.x = a.x + b.x; o.y = a.y + b.y; o.z = a.z + b.z; o.w = a.w + b.w;
  ((float4*)out)[i] = o;
}

// ============ 256x192 2-phase GEMM (full-fill shape for M=2048, N=6144) ============
// BM=256, BN=192, BK=64, 512 threads = 8 waves (2Mx4N); per-wave output 128x48.
// Grid = 8 x 32 = 256 blocks = exactly 1/CU. LDS 112 KB: A 2x(2x16KB halves), B 2x24KB.
// G4 swizzle byte ^= ((row&7)<<4) via pre-swizzled gl16 source + swizzled ds_read col.
// Phases per K-tile: ph1 {read A-h0 + B, stage B(t+1), 24 MFMA}; ph2 {read A-h1,
// stage A-h0(t+2), 24 MFMA}; boundary {stage A-h1(t+2), vmcnt(4), barrier}.
__global__ __launch_bounds__(512, 2) void k_gemm192(const unsigned short* __restrict__ A,
                                                    const unsigned short* __restrict__ B,
                                                    float* __restrict__ C,
                                                    int M, int N, int K) {
  extern __shared__ __align__(16) unsigned short smem[];
  char* Sc = (char*)smem;
  const int tid = threadIdx.x;
  const int wvid = tid >> 6, l = tid & 63;
  const int wm = wvid >> 2, wn = wvid & 3;
  const int l15 = l & 15, l4 = l >> 4;

  // XCD-bijective swizzle (nwg = 256)
  const int nwg = gridDim.x;
  const int cpx = nwg >> 3;
  const int bid = blockIdx.x;
  const int swz = (bid & 7) * cpx + (bid >> 3);
  const int mtiles = M >> 8;
  const int m0 = (swz % mtiles) * 256;
  const int n0 = (swz / mtiles) * 192;

  const int NT = K >> 6;

  const int rsw = (l15 & 7) << 4;
  const int a_base = (wm * 64 + l15) * 128;   // + fm*2048 + c{0,1}, within 16KB half
  const int b_base = (wn * 48 + l15) * 128;   // + fn*2048 + c{0,1}, within 24KB tile
  const int c0 = (l4 * 16) ^ rsw;
  const int c1 = (64 + l4 * 16) ^ rsw;

  // stage-side: dest (row = blk*8 + l>>3, slot = l&7) <- global k8 = (l&7)^(l>>3)
  const int st_row = l >> 3;
  const int st_k8 = (l & 7) ^ st_row;

  auto stA = [&](int tt, int h) {  // 16 KB half: 2 gl16 per thread
    if (tt >= NT) return;
    const unsigned short* g = A + (size_t)(m0 + h * 128) * K + tt * 64 + st_k8 * 8;
    unsigned short* lb = (unsigned short*)(Sc + (tt & 1) * 32768 + h * 16384);
#pragma unroll
    for (int j = 0; j < 2; ++j) {
      int blk = j * 8 + wvid;
      gl16(g + (size_t)(blk * 8 + st_row) * K, lb + blk * 512);
    }
  };
  auto stB = [&](int tt) {  // 24 KB tile: 3 gl16 per thread
    if (tt >= NT) return;
    const unsigned short* g = B + (size_t)n0 * K + tt * 64 + st_k8 * 8;
    unsigned short* lb = (unsigned short*)(Sc + 65536 + (tt & 1) * 24576);
#pragma unroll
    for (int j = 0; j < 3; ++j) {
      int blk = j * 8 + wvid;
      gl16(g + (size_t)(blk * 8 + st_row) * K, lb + blk * 512);
    }
  };

  f32x4 acc[2][4][3] = {};

  // ---- prologue: t0 fully, then t1's A halves (B(1) comes in iter0 ph1) ----
  stA(0, 0); stA(0, 1); stB(0);
  stA(1, 0); stA(1, 1);
  if (NT > 1) asm volatile("s_waitcnt vmcnt(4)" ::: "memory");
  else        asm volatile("s_waitcnt vmcnt(0)" ::: "memory");
  __builtin_amdgcn_s_barrier();

  for (int t = 0; t < NT; ++t) {
    const int b = t & 1;
    const char* Ab = Sc + b * 32768;
    const char* Bb = Sc + 65536 + b * 24576;
    bf16x8 a[4][2], bb[3][2];

    // ===== phase 1: A-h0 x B — read A-h0(8) + B(6); stage B(t+1) =====
#pragma unroll
    for (int fm = 0; fm < 4; ++fm) {
      a[fm][0] = *(const bf16x8*)(Ab + a_base + fm * 2048 + c0);
      a[fm][1] = *(const bf16x8*)(Ab + a_base + fm * 2048 + c1);
    }
#pragma unroll
    for (int fn = 0; fn < 3; ++fn) {
      bb[fn][0] = *(const bf16x8*)(Bb + b_base + fn * 2048 + c0);
      bb[fn][1] = *(const bf16x8*)(Bb + b_base + fn * 2048 + c1);
    }
    stB(t + 1);
    __builtin_amdgcn_s_barrier();
    __builtin_amdgcn_s_setprio(1);
#pragma unroll
    for (int fm = 0; fm < 4; ++fm)
#pragma unroll
      for (int fn = 0; fn < 3; ++fn)
#pragma unroll
        for (int ks = 0; ks < 2; ++ks)
          acc[0][fm][fn] = __builtin_amdgcn_mfma_f32_16x16x32_bf16(a[fm][ks], bb[fn][ks], acc[0][fm][fn], 0, 0, 0);
    __builtin_amdgcn_s_setprio(0);
    __builtin_amdgcn_s_barrier();

    // ===== phase 2: A-h1 x B — read A-h1(8); stage A-h0(t+2); B held in regs =====
#pragma unroll
    for (int fm = 0; fm < 4; ++fm) {
      a[fm][0] = *(const bf16x8*)(Ab + 16384 + a_base + fm * 2048 + c0);
      a[fm][1] = *(const bf16x8*)(Ab + 16384 + a_base + fm * 2048 + c1);
    }
    stA(t + 2, 0);
    __builtin_amdgcn_s_barrier();
    __builtin_amdgcn_s_setprio(1);
#pragma unroll
    for (int fm = 0; fm < 4; ++fm)
#pragma unroll
      for (int fn = 0; fn < 3; ++fn)
#pragma unroll
        for (int ks = 0; ks < 2; ++ks)
          acc[1][fm][fn] = __builtin_amdgcn_mfma_f32_16x16x32_bf16(a[fm][ks], bb[fn][ks], acc[1][fm][fn], 0, 0, 0);
    __builtin_amdgcn_s_setprio(0);
    __builtin_amdgcn_s_barrier();

    // ===== boundary: stage A-h1(t+2) (reads of h1 all consumed); counted vmcnt =====
    stA(t + 2, 1);
    if (t + 1 < NT) {
      if (t + 1 == NT - 1) asm volatile("s_waitcnt vmcnt(0)" ::: "memory");
      else                 asm volatile("s_waitcnt vmcnt(4)" ::: "memory");
      __builtin_amdgcn_s_barrier();
    }
  }

  // ---- epilogue: C write ----
#pragma unroll
  for (int h = 0; h < 2; ++h)
#pragma unroll
    for (int fm = 0; fm < 4; ++fm) {
      int row0 = m0 + h * 128 + wm * 64 + fm * 16 + l4 * 4;
#pragma unroll
      for (int fn = 0; fn < 3; ++fn) {
        int col = n0 + wn * 48 + fn * 16 + l15;
#pragma unroll
        for (int r = 0; r < 4; ++r)
          C[(size_t)(row0 + r) * N + col] = acc[h][fm][fn][r];
      }
    }
}

// ============ 256x256 4-phase GEMM (+ in-grid split-K) — used for out-proj ============
__global__ __launch_bounds__(512, 2) void k_gemm256(const unsigned short* __restrict__ A,
                                                    const unsigned short* __restrict__ B,
                                                    float* __restrict__ C,
                                                    int M, int N, int K, int kchunk) {
  extern __shared__ __align__(16) unsigned short smem[];
  char* Sc = (char*)smem;
  const int tid = threadIdx.x;
  const int wvid = tid >> 6, l = tid & 63;
  const int wm = wvid >> 2, wn = wvid & 3;
  const int l15 = l & 15, l4 = l >> 4;

  const int nwg = gridDim.x;
  const int cpx = nwg >> 3;
  const int bid = blockIdx.x;
  const int swz = (bid & 7) * cpx + (bid >> 3);
  const int mtiles = M >> 8;
  const int ntiles = N >> 8;
  const int sidx = swz / (mtiles * ntiles);
  const int rem = swz % (mtiles * ntiles);
  const int m0 = (rem % mtiles) * 256;
  const int n0 = (rem / mtiles) * 256;

  const unsigned short* Ab_g = A + (size_t)sidx * kchunk;
  const unsigned short* Bb_g = B + (size_t)sidx * kchunk;
  float* Cb = C + (size_t)sidx * M * N;
  const int NT = kchunk >> 6;

  const int rsw = (l15 & 7) << 4;
  const int a_base = (wm * 64 + l15) * 128;
  const int b_base = (wn * 32 + l15) * 128;
  const int c0 = (l4 * 16) ^ rsw;
  const int c1 = (64 + l4 * 16) ^ rsw;

  const int st_row = l >> 3;
  const int st_k8 = (l & 7) ^ st_row;

  auto stA = [&](int tt, int h) {
    if (tt >= NT) return;
    const unsigned short* g = Ab_g + (size_t)(m0 + h * 128) * K + tt * 64 + st_k8 * 8;
    unsigned short* lb = (unsigned short*)(Sc + (tt & 1) * 32768 + h * 16384);
#pragma unroll
    for (int j = 0; j < 2; ++j) {
      int blk = j * 8 + wvid;
      gl16(g + (size_t)(blk * 8 + st_row) * K, lb + blk * 512);
    }
  };
  auto stB = [&](int tt, int c) {
    if (tt >= NT) return;
    const unsigned short* g = Bb_g + (size_t)(n0 + c * 128) * K + tt * 64 + st_k8 * 8;
    unsigned short* lb = (unsigned short*)(Sc + 65536 + (tt & 1) * 32768 + c * 16384);
#pragma unroll
    for (int j = 0; j < 2; ++j) {
      int blk = j * 8 + wvid;
      gl16(g + (size_t)(blk * 8 + st_row) * K, lb + blk * 512);
    }
  };

  f32x4 acc[2][4][2][2] = {};

  stA(0, 0); stB(0, 1); stA(0, 1); stB(0, 0);
  stA(1, 0); stB(1, 1); stA(1, 1);
  if (NT > 1) asm volatile("s_waitcnt vmcnt(6)" ::: "memory");
  else        asm volatile("s_waitcnt vmcnt(0)" ::: "memory");
  __builtin_amdgcn_s_barrier();

  for (int t = 0; t < NT; ++t) {
    const int b = t & 1;
    const char* Ab = Sc + b * 32768;
    const char* Bb = Sc + 65536 + b * 32768;
    bf16x8 a[4][2], bbl[2][2], bbh[2][2];

    // ===== phase 1: (h0,c0) — read A-h0(8) + B-h0(4, held for ph4); stage B0(t+1) =====
#pragma unroll
    for (int fm = 0; fm < 4; ++fm) {
      a[fm][0] = *(const bf16x8*)(Ab + a_base + fm * 2048 + c0);
      a[fm][1] = *(const bf16x8*)(Ab + a_base + fm * 2048 + c1);
    }
#pragma unroll
    for (int fn = 0; fn < 2; ++fn) {
      bbl[fn][0] = *(const bf16x8*)(Bb + b_base + fn * 2048 + c0);
      bbl[fn][1] = *(const bf16x8*)(Bb + b_base + fn * 2048 + c1);
    }
    stB(t + 1, 0);
    __builtin_amdgcn_s_barrier();
    __builtin_amdgcn_s_setprio(1);
#pragma unroll
    for (int fm = 0; fm < 4; ++fm)
#pragma unroll
      for (int fn = 0; fn < 2; ++fn)
#pragma unroll
        for (int ks = 0; ks < 2; ++ks)
          acc[0][fm][0][fn] = __builtin_amdgcn_mfma_f32_16x16x32_bf16(a[fm][ks], bbl[fn][ks], acc[0][fm][0][fn], 0, 0, 0);
    __builtin_amdgcn_s_setprio(0);
    __builtin_amdgcn_s_barrier();

    // ===== phase 2: (h0,c1) — read B-h1(4); stage A0(t+2) =====
#pragma unroll
    for (int fn = 0; fn < 2; ++fn) {
      bbh[fn][0] = *(const bf16x8*)(Bb + 16384 + b_base + fn * 2048 + c0);
      bbh[fn][1] = *(const bf16x8*)(Bb + 16384 + b_base + fn * 2048 + c1);
    }
    stA(t + 2, 0);
    __builtin_amdgcn_s_barrier();
    __builtin_amdgcn_s_setprio(1);
#pragma unroll
    for (int fm = 0; fm < 4; ++fm)
#pragma unroll
      for (int fn = 0; fn < 2; ++fn)
#pragma unroll
        for (int ks = 0; ks < 2; ++ks)
          acc[0][fm][1][fn] = __builtin_amdgcn_mfma_f32_16x16x32_bf16(a[fm][ks], bbh[fn][ks], acc[0][fm][1][fn], 0, 0, 0);
    __builtin_amdgcn_s_setprio(0);
    __builtin_amdgcn_s_barrier();

    // ===== phase 3: (h1,c1) — read A-h1(8); stage B1(t+2); B-h1 held in regs =====
#pragma unroll
    for (int fm = 0; fm < 4; ++fm) {
      a[fm][0] = *(const bf16x8*)(Ab + 16384 + a_base + fm * 2048 + c0);
      a[fm][1] = *(const bf16x8*)(Ab + 16384 + a_base + fm * 2048 + c1);
    }
    stB(t + 2, 1);
    __builtin_amdgcn_s_barrier();
    __builtin_amdgcn_s_setprio(1);
#pragma unroll
    for (int fm = 0; fm < 4; ++fm)
#pragma unroll
      for (int fn = 0; fn < 2; ++fn)
#pragma unroll
        for (int ks = 0; ks < 2; ++ks)
          acc[1][fm][1][fn] = __builtin_amdgcn_mfma_f32_16x16x32_bf16(a[fm][ks], bbh[fn][ks], acc[1][fm][1][fn], 0, 0, 0);
    __builtin_amdgcn_s_setprio(0);
    __builtin_amdgcn_s_barrier();

    // ===== phase 4: (h1,c0) — B-h0 held from ph1; stage A1(t+2); boundary vmcnt =====
    stA(t + 2, 1);
    __builtin_amdgcn_s_setprio(1);
#pragma unroll
    for (int fm = 0; fm < 4; ++fm)
#pragma unroll
      for (int fn = 0; fn < 2; ++fn)
#pragma unroll
        for (int ks = 0; ks < 2; ++ks)
          acc[1][fm][0][fn] = __builtin_amdgcn_mfma_f32_16x16x32_bf16(a[fm][ks], bbl[fn][ks], acc[1][fm][0][fn], 0, 0, 0);
    __builtin_amdgcn_s_setprio(0);
    if (t + 1 < NT) {
      if (t + 1 == NT - 1) asm volatile("s_waitcnt vmcnt(0)" ::: "memory");
      else                 asm volatile("s_waitcnt vmcnt(6)" ::: "memory");
    }
    __builtin_amdgcn_s_barrier();
  }

#pragma unroll
  for (int h = 0; h < 2; ++h)
#pragma unroll
    for (int fm = 0; fm < 4; ++fm) {
      int row0 = m0 + h * 128 + wm * 64 + fm * 16 + l4 * 4;
#pragma unroll
      for (int c = 0; c < 2; ++c)
#pragma unroll
        for (int fn = 0; fn < 2; ++fn) {
          int col = n0 + c * 128 + wn * 32 + fn * 16 + l15;
#pragma unroll
          for (int r = 0; r < 4; ++r)
            Cb[(size_t)(row0 + r) * N + col] = acc[h][fm][c][fn][r];
        }
    }
}

// ------------- RoPE + int8 quantize (stored as bf16 ints) -------------
__global__ __launch_bounds__(256) void k_ropequant(const float* __restrict__ qkv,
                                                   const float* __restrict__ cost,
                                                   const float* __restrict__ sint,
                                                   unsigned short* __restrict__ q_int,
                                                   float* __restrict__ q_ds,
                                                   unsigned short* __restrict__ k_int,
                                                   float* __restrict__ k_ds,
                                                   unsigned short* __restrict__ v_bf) {
  int s = blockIdx.x;
  int wv = threadIdx.x >> 6, l = threadIdx.x & 63;
  int hh = blockIdx.y * 4 + wv;  // 0..47: [0,32) q, [32,40) k, [40,48) v
  const float* row = qkv + (size_t)s * NQKV;
  if (hh < NH + NKV) {
    int off = (hh < NH) ? hh * HD : DMODEL + (hh - NH) * HD;
    float t1 = row[off + l], t2 = row[off + 64 + l];
    float c1 = cost[s * HD + l],      sn1 = sint[s * HD + l];
    float c2 = cost[s * HD + 64 + l], sn2 = sint[s * HD + 64 + l];
    float o1 = t1 * c1 - t2 * sn1;
    float o2 = t2 * c2 + t1 * sn2;
    float amax = fmaxf(fabsf(o1), fabsf(o2));
#pragma unroll
    for (int m = 1; m < 64; m <<= 1) amax = fmaxf(amax, __shfl_xor(amax, m));
    amax = fmaxf(amax, 1e-5f);
    float scale = 127.0f / amax;
    float dscale = amax * (1.0f / 127.0f);
    float v1 = fminf(fmaxf(rintf(o1 * scale), -128.f), 127.f);
    float v2 = fminf(fmaxf(rintf(o2 * scale), -128.f), 127.f);
    if (hh < NH) {
      unsigned short* dst = q_int + ((size_t)s * NH + hh) * HD;
      dst[l] = f2b(v1); dst[l + 64] = f2b(v2);
      if (l == 0) q_ds[(size_t)s * NH + hh] = dscale;
    } else {
      int kh = hh - NH;
      unsigned short* dst = k_int + ((size_t)s * NKV + kh) * HD;
      dst[l] = f2b(v1); dst[l + 64] = f2b(v2);
      if (l == 0) k_ds[(size_t)s * NKV + kh] = dscale;
    }
  } else {
    int vh = hh - (NH + NKV);
    const float* src = row + DMODEL + NKV * HD + vh * HD;
    unsigned short* dst = v_bf + ((size_t)s * NKV + vh) * HD;
    dst[l] = f2b(src[l]);
    dst[l + 64] = f2b(src[l + 64]);
  }
}

// ------------- causal GQA flash attention, paired q-tiles, async dbuf staging -------------
__global__ __launch_bounds__(256) void k_attn(const unsigned short* __restrict__ q_int,
                                              const float* __restrict__ q_ds,
                                              const unsigned short* __restrict__ k_int,
                                              const float* __restrict__ k_ds,
                                              const unsigned short* __restrict__ v_t,
                                              unsigned short* __restrict__ o_bf) {
  __shared__ __align__(16) unsigned short K_lds[2][8192];
  __shared__ __align__(16) unsigned short V_lds[2][8192];
  __shared__ __align__(16) unsigned short P_lds[4][16 * 72];

  const int bid = blockIdx.x;
  const int kvh = bid & 7;
  const int h = kvh * 4 + ((bid >> 3) & 3);
  const int bx = bid >> 5;
  const int tid = threadIdx.x, wv = tid >> 6, l = tid & 63;
  const int l15 = l & 15, l4 = l >> 4;

  auto stage = [&](int b, int kt) {
    const unsigned short* kB = k_int + (size_t)kt * 64 * (NKV * HD) + kvh * HD;
    const unsigned short* vB = v_t + (size_t)kvh * HD * S_LEN + (size_t)kt * 64;
#pragma unroll
    for (int j = 0; j < 4; ++j) {
      int wi = j * 4 + wv;
      int slot = wi * 64 + l;
      int key = slot >> 4;
      int colb = ((slot & 15) * 16) ^ ((key & 7) << 4);
      gl16(kB + key * (NKV * HD) + (colb >> 1), &K_lds[b][wi * 512]);
      int d = slot >> 3;
      int ckb = ((slot & 7) * 16) ^ ((d & 7) << 4);
      gl16(vB + (size_t)d * S_LEN + (ckb >> 1), &V_lds[b][wi * 512]);
    }
  };

  for (int ph = 0; ph < 2; ++ph) {
    const int qt = ph ? bx : (31 - bx);
    const int q0 = qt * 64;
    const int qrow_lo = q0 + wv * 16;
    const int crow = qrow_lo + l4 * 4;

    bf16x8 qf[4];
    {
      const unsigned short* qp = q_int + ((size_t)(qrow_lo + l15) * NH + h) * HD + l4 * 8;
#pragma unroll
      for (int kd = 0; kd < 4; ++kd) qf[kd] = *(const bf16x8*)(qp + kd * 32);
    }
    float qsS[4];
#pragma unroll
    for (int r = 0; r < 4; ++r) qsS[r] = ATT_SCALE * q_ds[(size_t)(crow + r) * NH + h];

    float m_run[4], l_run[4];
    f32x4 o_acc[8] = {};
#pragma unroll
    for (int r = 0; r < 4; ++r) { m_run[r] = -3.0e38f; l_run[r] = 0.f; }

    const int nkt = qt + 1;
    stage(0, 0);
    __syncthreads();

    for (int kt = 0; kt < nkt; ++kt) {
      const int cur = kt & 1;
      float ksd[4];
#pragma unroll
      for (int nt = 0; nt < 4; ++nt)
        ksd[nt] = k_ds[(size_t)(kt * 64 + nt * 16 + l15) * NKV + kvh];
      if (kt + 1 < nkt) stage(cur ^ 1, kt + 1);

      f32x4 sacc[4] = {};
#pragma unroll
      for (int nt = 0; nt < 4; ++nt) {
        int key = nt * 16 + l15;
#pragma unroll
        for (int kd = 0; kd < 4; ++kd) {
          int byte = key * 256 + kd * 64 + l4 * 16;
          byte ^= (key & 7) << 4;
          bf16x8 kf = *(const bf16x8*)((const char*)&K_lds[cur][0] + byte);
          sacc[nt] = __builtin_amdgcn_mfma_f32_16x16x32_bf16(qf[kd], kf, sacc[nt], 0, 0, 0);
        }
      }

      float p[4][4];
      float tmax[4] = {-3.0e38f, -3.0e38f, -3.0e38f, -3.0e38f};
#pragma unroll
      for (int nt = 0; nt < 4; ++nt) {
        int keyg = kt * 64 + nt * 16 + l15;
#pragma unroll
        for (int r = 0; r < 4; ++r) {
          float sc = sacc[nt][r] * (qsS[r] * ksd[nt]);
          sc = (keyg <= crow + r) ? sc : -3.0e38f;
          p[nt][r] = sc;
          tmax[r] = fmaxf(tmax[r], sc);
        }
      }
#pragma unroll
      for (int m = 1; m < 16; m <<= 1)
#pragma unroll
        for (int r = 0; r < 4; ++r) tmax[r] = fmaxf(tmax[r], __shfl_xor(tmax[r], m));
      float corr[4], psum[4];
#pragma unroll
      for (int r = 0; r < 4; ++r) {
        float mnew = fmaxf(m_run[r], tmax[r]);
        corr[r] = __expf(m_run[r] - mnew);
        m_run[r] = mnew;
        l_run[r] *= corr[r];
        psum[r] = 0.f;
      }
#pragma unroll
      for (int nt = 0; nt < 4; ++nt)
#pragma unroll
        for (int r = 0; r < 4; ++r) {
          float e = __expf(p[nt][r] - m_run[r]);
          p[nt][r] = e;
          psum[r] += e;
        }
#pragma unroll
      for (int m = 1; m < 16; m <<= 1)
#pragma unroll
        for (int r = 0; r < 4; ++r) psum[r] += __shfl_xor(psum[r], m);
#pragma unroll
      for (int r = 0; r < 4; ++r) l_run[r] += psum[r];
#pragma unroll
      for (int dt = 0; dt < 8; ++dt)
#pragma unroll
        for (int r = 0; r < 4; ++r) o_acc[dt][r] *= corr[r];

#pragma unroll
      for (int nt = 0; nt < 4; ++nt)
#pragma unroll
        for (int r = 0; r < 4; ++r)
          P_lds[wv][(l4 * 4 + r) * 72 + nt * 16 + l15] = f2b(p[nt][r]);

      bf16x8 pa[2];
#pragma unroll
      for (int kc = 0; kc < 2; ++kc)
        pa[kc] = *(const bf16x8*)((const char*)&P_lds[wv][0] + l15 * 144 + kc * 64 + l4 * 16);

#pragma unroll
      for (int dt = 0; dt < 8; ++dt) {
        int d = dt * 16 + l15;
        int swzv = (d & 7) << 4;
#pragma unroll
        for (int kc = 0; kc < 2; ++kc) {
          int byte = d * 128 + ((kc * 64 + l4 * 16) ^ swzv);
          bf16x8 vb = *(const bf16x8*)((const char*)&V_lds[cur][0] + byte);
          o_acc[dt] = __builtin_amdgcn_mfma_f32_16x16x32_bf16(pa[kc], vb, o_acc[dt], 0, 0, 0);
        }
      }
      __syncthreads();
    }

    float inv_l[4];
#pragma unroll
    for (int r = 0; r < 4; ++r) inv_l[r] = 1.0f / l_run[r];
#pragma unroll
    for (int dt = 0; dt < 8; ++dt)
#pragma unroll
      for (int r = 0; r < 4; ++r)
        o_bf[(size_t)(crow + r) * (NH * HD) + h * HD + dt * 16 + l15] = f2b(o_acc[dt][r] * inv_l[r]);
  }
}

extern "C" void kernel_launch(void* const* d_in, const int* in_sizes, int n_in,
                              void* d_out, int out_size, void* d_ws, size_t ws_size,
                              hipStream_t stream) {
  const float* x    = (const float*)d_in[0];
  const float* Wq   = (const float*)d_in[1];
  const float* Wk   = (const float*)d_in[2];
  const float* Wv   = (const float*)d_in[3];
  const float* Wo   = (const float*)d_in[4];
  const float* cost = (const float*)d_in[5];
  const float* sint = (const float*)d_in[6];
  float* out = (float*)d_out;
  char* ws = (char*)d_ws;

  unsigned short* xb     = (unsigned short*)(ws);                 // 16 MB (dead after gemm1)
  unsigned short* wqkv_t = (unsigned short*)(ws + 16777216);      // 48 MB (dead after gemm1)
  unsigned short* wo_t   = (unsigned short*)(ws + 67108864);      // 32 MB (4096x4096)
  float*          qkv    = (float*)(ws + 100663296);              // 48 MB (dead after ropequant)
  unsigned short* q_int  = (unsigned short*)(ws + 150994944);     // 16 MB
  unsigned short* k_int  = (unsigned short*)(ws + 167772160);     // 4 MB
  unsigned short* v_bf   = (unsigned short*)(ws + 171966464);     // 4 MB
  float*          q_ds   = (float*)(ws + 176160768);              // 256 KB
  float*          k_ds   = (float*)(ws + 176422912);              // 64 KB
  unsigned short* o_bf   = (unsigned short*)(ws + 176488448);     // 16 MB
  unsigned short* v_t    = (unsigned short*)(ws);                 // 4 MB, aliases dead xb
  float*          part   = (float*)(ws + 16777216);               // 64 MB split-K partials,
                                                                  // aliases dead wqkv_t+qkv

  hipFuncSetAttribute((const void*)k_gemm192,
                      hipFuncAttributeMaxDynamicSharedMemorySize, 114688);
  hipFuncSetAttribute((const void*)k_gemm256,
                      hipFuncAttributeMaxDynamicSharedMemorySize, 131072);

  k_cvt_x<<<(S_LEN * DMODEL / 4) / 256, 256, 0, stream>>>(x, xb);
  k_transpose<<<dim3(64, 64), 256, 0, stream>>>(Wq, wqkv_t, 4096, 4096);
  k_transpose<<<dim3(64, 16), 256, 0, stream>>>(Wk, wqkv_t + (size_t)4096 * 4096, 4096, 1024);
  k_transpose<<<dim3(64, 16), 256, 0, stream>>>(Wv, wqkv_t + (size_t)5120 * 4096, 4096, 1024);
  k_transpose<<<dim3(64, 64), 256, 0, stream>>>(Wo, wo_t, 4096, 4096);
  // QKV proj: 256x192 tiles -> 8 x 32 = 256 blocks = exact full-CU fill
  k_gemm192<<<dim3(256), 512, 114688, stream>>>(xb, wqkv_t, qkv, 2048, 6144, 4096);
  k_ropequant<<<dim3(2048, 12), 256, 0, stream>>>(qkv, cost, sint, q_int, q_ds, k_int, k_ds, v_bf);
  k_vt<<<dim3(32, 2, 8), 256, 0, stream>>>(v_bf, v_t);
  k_attn<<<dim3(512), 256, 0, stream>>>(q_int, q_ds, k_int, k_ds, v_t, o_bf);
  // out-proj: split-K x2 -> 256 blocks (full CU fill), then fixup sum
  k_gemm256<<<dim3(256), 512, 131072, stream>>>(o_bf, wo_t, part, 2048, 4096, 4096, 2048);
  k_sum2<<<dim3(8192), 256, 0, stream>>>(part, part + (size_t)2048 * 4096, out);
}